// Round 25
// baseline (172.003 us; speedup 1.0000x reference)
//
#include <hip/hip_runtime.h>
#include <math.h>

#define DD 128
#define HW 512
#define MG 514

// Verified reference stack (r10/r11/r14): G1 predux-tree colmajor conv,
// contract-off mul/add mag, fd-hybrid classifier.
// r25: k_fused bitmask hysteresis + packed classes; k_max1 8-col full-width
// (no halo loads, edge mags from broadcasts). Bit-identical arithmetic.

static __device__ float fd_atanf(float x) {
    #pragma clang fp contract(off)
    const unsigned hx = __float_as_uint(x);
    const unsigned ix = hx & 0x7fffffffu;
    const double A0 = 0.46364760900080611621425623146121440203;
    const double A1 = 0.78539816339744830961566084581987572105;
    const double A2 = 0.98279372324732906798571061101466601449;
    const double A3 = 1.57079632679489661923132169163975144210;
    const float aT0 =  3.3333328366e-01f;
    const float aT1 = -1.9999158382e-01f;
    const float aT2 =  1.4253635705e-01f;
    const float aT3 = -1.0648017377e-01f;
    const float aT4 =  6.1687607318e-02f;
    float z, w, s1, s2;
    int id;
    double a;
    if (ix >= 0x4c800000u) {
        a = A3;
        float hi = (float)a; if ((double)hi > a) hi = __uint_as_float(__float_as_uint(hi) - 1u);
        float lo = (float)(a - (double)hi);
        float r = hi + lo;
        return (hx >> 31) ? -r : r;
    }
    if (ix < 0x3ee00000u) {
        if (ix < 0x39800000u) return x;
        id = -1;
    } else {
        x = fabsf(x);
        if (ix < 0x3f980000u) {
            if (ix < 0x3f300000u) { id = 0; x = (2.0f * x - 1.0f) / (2.0f + x); }
            else                  { id = 1; x = (x - 1.0f) / (x + 1.0f); }
        } else {
            if (ix < 0x401c0000u) { id = 2; x = (x - 1.5f) / (1.0f + 1.5f * x); }
            else                  { id = 3; x = -1.0f / x; }
        }
    }
    z = x * x;
    w = z * z;
    s1 = z * (aT0 + w * (aT2 + w * aT4));
    s2 = w * (aT1 + w * aT3);
    if (id < 0) return x - x * (s1 + s2);
    a = (id == 0) ? A0 : (id == 1) ? A1 : (id == 2) ? A2 : A3;
    float hi = (float)a; if ((double)hi > a) hi = __uint_as_float(__float_as_uint(hi) - 1u);
    float lo = (float)(a - (double)hi);
    z = hi - ((x * (s1 + s2) - lo) - x);
    return (hx >> 31) ? -z : z;
}

static __device__ __noinline__ int cls_fd(float y, float x) {
    #pragma clang fp contract(off)
    const unsigned hx = __float_as_uint(x), hy = __float_as_uint(y);
    const unsigned ix = hx & 0x7fffffffu, iy = hy & 0x7fffffffu;
    unsigned m = ((hy >> 31) & 1u) | ((hx >> 30) & 2u);
    const double PI_D = 3.14159265358979323846264338327950288420;
    const float pi_f  = (float)PI_D;
    const float pi_lo = (float)(PI_D - (double)pi_f);
    const float pi4_f = (float)(PI_D / 4.0);
    const float pi2_f = (float)(PI_D / 2.0);
    float v;
    if (iy == 0) {
        v = (m == 0 || m == 1) ? y : (m == 2 ? pi_f : -pi_f);
    } else if (ix == 0) {
        v = (m & 1u) ? -pi2_f : pi2_f;
    } else if (ix + (26u << 23) < iy) {
        v = (m & 1u) ? -pi2_f : pi2_f;
    } else {
        float z;
        if ((m & 2u) && iy + (26u << 23) < ix) z = 0.0f;
        else z = fd_atanf(fabsf(y / x));
        switch (m) {
            case 0:  v = z; break;
            case 1:  v = -z; break;
            case 2:  v = pi_f - (z - pi_lo); break;
            default: v = (z - pi_lo) - pi_f; break;
        }
    }
    float t = v / pi4_f;
    int n = (int)rintf(t);
    return n & 3;
}

static __device__ __forceinline__ int classify(float gx, float gy) {
    #pragma clang fp contract(off)
    float ax = fabsf(gx), ay = fabsf(gy);
    const float T = 0.41421356237309504880f;
    float r1 = ay - ax * T;
    float r2 = ax - ay * T;
    float eps = 1e-4f * (ax + ay);
    if (fabsf(r1) > eps && fabsf(r2) > eps) {
        if (r1 < 0.0f) return 0;
        if (r2 < 0.0f) return 2;
        return ((__float_as_uint(gx) ^ __float_as_uint(gy)) >> 31) ? 3 : 1;
    }
    return cls_fd(gy, gx);
}

static __device__ __forceinline__ void grad_g1v(float x00, float x01, float x02,
                                                float x10, float x12,
                                                float x20, float x21, float x22,
                                                float& gx, float& gy) {
    #pragma clang fp contract(off)
    { float A = -x00; float B = x02 + (-x20); float C = 2.0f*x12; float D = -2.0f*x10;
      float E = A + B; float F = C + D; gx = (E + F) + x22; }
    { float A = -x00; float B = (-x02) + x20; float C = -2.0f*x01; float D = 2.0f*x21;
      float E = A + B; float F = C + D; gy = (E + F) + x22; }
}

static __device__ __forceinline__ float mag2(float gx, float gy) {
    #pragma clang fp contract(off)
    float p = gx * gx;
    float q = gy * gy;
    return sqrtf(p + q);
}
static __device__ __forceinline__ float sq2(float gx, float gy) {
    #pragma clang fp contract(off)
    float p = gx * gx;
    float q = gy * gy;
    return p + q;
}

// ================= pass 1: per-slice max of gx^2+gy^2 (8 cols/lane) =================
#define M1LOAD(S_, ROWEXPR) do {                                                      \
    int W_ = (ROWEXPR); W_ += (W_ < 0) ? MG : 0; W_ -= (W_ >= MG) ? MG : 0;           \
    float4 a_ = {0.f,0.f,0.f,0.f}, b_ = {0.f,0.f,0.f,0.f};                            \
    if ((unsigned)(W_ - 1) < (unsigned)HW) {                                          \
        const float* rp_ = xd + (size_t)(W_ - 1) * HW + 8 * lane;                     \
        a_ = *(const float4*)rp_;  b_ = *(const float4*)(rp_ + 4);                    \
    }                                                                                 \
    X0[S_]=a_.x; X1[S_]=a_.y; X2[S_]=a_.z; X3[S_]=a_.w;                               \
    X4[S_]=b_.x; X5[S_]=b_.y; X6[S_]=b_.z; X7[S_]=b_.w;                               \
    float xl_ = __shfl_up(b_.w, 1);   if (L0)  xl_ = 0.0f;                            \
    float xr_ = __shfl_down(a_.x, 1); if (L63) xr_ = 0.0f;                            \
    Xl[S_] = xl_; Xr[S_] = xr_;                                                       \
    B0[S_] = __shfl(a_.x, 0);  B7[S_] = __shfl(b_.w, 63);                             \
} while (0)

#define M1G(p0,p1,p2,q1,r0,r1,r2) do {                                                \
    float gx_, gy_;                                                                   \
    grad_g1v(p0, p1, p2, q1##a, q1##b, r0, r1, r2, gx_, gy_);                         \
    acc = fmaxf(acc, sq2(gx_, gy_));                                                  \
} while (0)

#define M1BODY(kk, S, DOMAG) do {                                                     \
    constexpr int s_ = (S);                                                           \
    constexpr int u0 = (s_ + 1) % 3, u1 = (s_ + 2) % 3, u2 = s_;                      \
    M1LOAD(s_, h0m - 1 + (kk));                                                       \
    if (DOMAG) {                                                                      \
        int Rm = h0m - 2 + (kk);                                                      \
        if (Rm <= 513) {                                                              \
            float gx_, gy_;                                                           \
            grad_g1v(Xl[u0],X0[u0],X1[u0], Xl[u1],X1[u1], Xl[u2],X0[u2],X1[u2],gx_,gy_); \
            acc = fmaxf(acc, sq2(gx_, gy_));                                          \
            grad_g1v(X0[u0],X1[u0],X2[u0], X0[u1],X2[u1], X0[u2],X1[u2],X2[u2],gx_,gy_); \
            acc = fmaxf(acc, sq2(gx_, gy_));                                          \
            grad_g1v(X1[u0],X2[u0],X3[u0], X1[u1],X3[u1], X1[u2],X2[u2],X3[u2],gx_,gy_); \
            acc = fmaxf(acc, sq2(gx_, gy_));                                          \
            grad_g1v(X2[u0],X3[u0],X4[u0], X2[u1],X4[u1], X2[u2],X3[u2],X4[u2],gx_,gy_); \
            acc = fmaxf(acc, sq2(gx_, gy_));                                          \
            grad_g1v(X3[u0],X4[u0],X5[u0], X3[u1],X5[u1], X3[u2],X4[u2],X5[u2],gx_,gy_); \
            acc = fmaxf(acc, sq2(gx_, gy_));                                          \
            grad_g1v(X4[u0],X5[u0],X6[u0], X4[u1],X6[u1], X4[u2],X5[u2],X6[u2],gx_,gy_); \
            acc = fmaxf(acc, sq2(gx_, gy_));                                          \
            grad_g1v(X5[u0],X6[u0],X7[u0], X5[u1],X7[u1], X5[u2],X6[u2],X7[u2],gx_,gy_); \
            acc = fmaxf(acc, sq2(gx_, gy_));                                          \
            grad_g1v(X6[u0],X7[u0],Xr[u0], X6[u1],Xr[u1], X6[u2],X7[u2],Xr[u2],gx_,gy_); \
            acc = fmaxf(acc, sq2(gx_, gy_));                                          \
            /* edge col 0: xs triplet (0,0,xs1); edge col 513: (xs512,0,0) */         \
            grad_g1v(0.0f,0.0f,B0[u0], 0.0f,B0[u1], 0.0f,0.0f,B0[u2], gx_, gy_);      \
            acc = fmaxf(acc, sq2(gx_, gy_));                                          \
            grad_g1v(B7[u0],0.0f,0.0f, B7[u1],0.0f, B7[u2],0.0f,0.0f, gx_, gy_);      \
            acc = fmaxf(acc, sq2(gx_, gy_));                                          \
        }                                                                             \
    }                                                                                 \
} while (0)

__global__ __launch_bounds__(256) void k_max1(const float* __restrict__ x,
                                              unsigned int* __restrict__ smax) {
    const int lane = threadIdx.x, ty = threadIdx.y;
    const int d  = blockIdx.z;
    const int h0m = (blockIdx.y * 4 + ty) * 9;       // 60 strips x 9 mag rows
    const float* xd = x + (size_t)d * HW * HW;
    const bool L0 = (lane == 0), L63 = (lane == 63);

    float X0[3],X1[3],X2[3],X3[3],X4[3],X5[3],X6[3],X7[3],Xl[3],Xr[3],B0[3],B7[3];
    float acc = 0.0f;

    M1BODY(0, 0, 0);  M1BODY(1, 1, 0);
    M1BODY(2, 2, 1);  M1BODY(3, 0, 1);  M1BODY(4, 1, 1);
    M1BODY(5, 2, 1);  M1BODY(6, 0, 1);  M1BODY(7, 1, 1);
    M1BODY(8, 2, 1);  M1BODY(9, 0, 1);  M1BODY(10, 1, 1);

    for (int off = 32; off > 0; off >>= 1)
        acc = fmaxf(acc, __shfl_down(acc, off, 64));
    if (lane == 0) {
        float mx = sqrtf(acc);   // CR sqrt monotone: sqrt(max sq) == max(sqrt sq)
        atomicMax(smax + d, __float_as_uint(mx));
    }
}

// ================= pass 2: fused (4 cols/lane, bitmask hysteresis) =================
#define LOADROW(S_, ROWEXPR) do {                                                     \
    int Rx_ = (ROWEXPR);                                                              \
    int W_ = Rx_;  W_ += (W_ < 0) ? MG : 0;  W_ -= (W_ >= MG) ? MG : 0;               \
    float4 xv_ = float4{0.f, 0.f, 0.f, 0.f}; float hv_ = 0.f;                         \
    if ((unsigned)(W_ - 1) < (unsigned)HW) {                                          \
        const float* rowp_ = xd + (size_t)(W_ - 1) * HW;                              \
        xv_ = *(const float4*)(rowp_ + j0 + 4 * lane);                                \
        if (hland && hok) hv_ = rowp_[hcolv];                                         \
    }                                                                                 \
    float hA_ = __shfl(hv_, 0),  hB_ = __shfl(hv_, 1),  hC_ = __shfl(hv_, 2);         \
    float hD_ = __shfl(hv_, 61), hE_ = __shfl(hv_, 62), hF_ = __shfl(hv_, 63);        \
    float xlv_ = __shfl_up(xv_.w, 1);   if (L0)  xlv_ = hC_;                          \
    float xrv_ = __shfl_down(xv_.x, 1); if (L63) xrv_ = hD_;                          \
    Xc0[S_] = xv_.x; Xc1[S_] = xv_.y; Xc2[S_] = xv_.z; Xc3[S_] = xv_.w;               \
    Xl[S_] = xlv_; Xr[S_] = xrv_;                                                     \
    E0[S_] = L0 ? hA_ : hD_; E1[S_] = L0 ? hB_ : hE_; E2[S_] = L0 ? hC_ : hF_;        \
} while (0)

#define MAGS6_F(u0, u1, u2, MAGFN)                                                    \
    float gx0, gy0, gx1, gy1, gx2, gy2, gx3, gy3;                                     \
    grad_g1v(Xl[u0], Xc0[u0], Xc1[u0], Xl[u1], Xc1[u1],                               \
             Xl[u2], Xc0[u2], Xc1[u2], gx0, gy0);                                     \
    grad_g1v(Xc0[u0], Xc1[u0], Xc2[u0], Xc0[u1], Xc2[u1],                             \
             Xc0[u2], Xc1[u2], Xc2[u2], gx1, gy1);                                    \
    grad_g1v(Xc1[u0], Xc2[u0], Xc3[u0], Xc1[u1], Xc3[u1],                             \
             Xc1[u2], Xc2[u2], Xc3[u2], gx2, gy2);                                    \
    grad_g1v(Xc2[u0], Xc3[u0], Xr[u0], Xc2[u1], Xr[u1],                               \
             Xc2[u2], Xc3[u2], Xr[u2], gx3, gy3);                                     \
    float m0_ = MAGFN(gx0, gy0), m1_ = MAGFN(gx1, gy1);                               \
    float m2_ = MAGFN(gx2, gy2), m3_ = MAGFN(gx3, gy3);                               \
    float A0_ = L0 ? E0[u0] : Xc3[u0], B0_ = L0 ? E1[u0] : E0[u0];                    \
    float C0_ = L0 ? E2[u0] : E1[u0],  D0_ = L0 ? Xc0[u0] : E2[u0];                   \
    float A1_ = L0 ? E0[u1] : Xc3[u1], B1_ = L0 ? E1[u1] : E0[u1];                    \
    float C1_ = L0 ? E2[u1] : E1[u1],  D1_ = L0 ? Xc0[u1] : E2[u1];                   \
    float A2_ = L0 ? E0[u2] : Xc3[u2], B2_ = L0 ? E1[u2] : E0[u2];                    \
    float C2_ = L0 ? E2[u2] : E1[u2],  D2_ = L0 ? Xc0[u2] : E2[u2];                   \
    float g1x, g1y, g2x, g2y;                                                         \
    grad_g1v(A0_, B0_, C0_, A1_, C1_, A2_, B2_, C2_, g1x, g1y);                       \
    grad_g1v(B0_, C0_, D0_, B1_, D1_, B2_, C2_, D2_, g2x, g2y);                       \
    float em1 = MAGFN(g1x, g1y), em2 = MAGFN(g2x, g2y);

#define P2BODY(kk, S, DO_MAG, DO_NMS, DO_OUT) do {                                    \
    constexpr int s_ = (S);                                                           \
    constexpr int sp1 = (s_ + 1) % 3, sp2 = (s_ + 2) % 3;                             \
    LOADROW(s_, h0 - 3 + (kk));                                                       \
    if (DO_MAG) {                                                                     \
        MAGS6_F(sp1, sp2, s_, mag2)                                                   \
        float mlv = __shfl_up(m3_, 1);   if (L0)  mlv = em2;                          \
        float mrv = __shfl_down(m0_, 1); if (L63) mrv = em1;                          \
        M0[sp1] = m0_; M1[sp1] = m1_; M2[sp1] = m2_; M3[sp1] = m3_;                   \
        Mlft[sp1] = mlv; Mrgt[sp1] = mrv;                                             \
        Emc[sp1] = L0 ? em2 : em1;                                                    \
        Eml[sp1] = L0 ? em1 : m3_;                                                    \
        Emr[sp1] = L0 ? m0_ : em2;                                                    \
        unsigned cp_ = (unsigned)classify(gx0, gy0)                                   \
                     | ((unsigned)classify(gx1, gy1) << 2)                            \
                     | ((unsigned)classify(gx2, gy2) << 4)                            \
                     | ((unsigned)classify(gx3, gy3) << 6)                            \
                     | ((unsigned)classify(L0 ? g2x : g1x, L0 ? g2y : g1y) << 8);     \
        CP[sp1] = cp_;                                                                \
    }                                                                                 \
    if (DO_NMS) {                                                                     \
        constexpr int w0 = sp2, w1 = s_, w2 = sp1;                                    \
        unsigned cpv = CP[w1];                                                        \
        float n0_, n1_, n2_, n3_;                                                     \
        { float m = M0[w1]; int c = cpv & 3;                                          \
          float a = (c==0)?Mlft[w1]:(c==1)?Mlft[w0]:(c==2)?M0[w0]:M1[w0];             \
          float b = (c==0)?M1[w1]:(c==1)?M1[w2]:(c==2)?M0[w2]:Mlft[w2];               \
          n0_ = (m >= a && m >= b) ? m : 0.0f; }                                      \
        { float m = M1[w1]; int c = (cpv >> 2) & 3;                                   \
          float a = (c==0)?M0[w1]:(c==1)?M0[w0]:(c==2)?M1[w0]:M2[w0];                 \
          float b = (c==0)?M2[w1]:(c==1)?M2[w2]:(c==2)?M1[w2]:M0[w2];                 \
          n1_ = (m >= a && m >= b) ? m : 0.0f; }                                      \
        { float m = M2[w1]; int c = (cpv >> 4) & 3;                                   \
          float a = (c==0)?M1[w1]:(c==1)?M1[w0]:(c==2)?M2[w0]:M3[w0];                 \
          float b = (c==0)?M3[w1]:(c==1)?M3[w2]:(c==2)?M2[w2]:M1[w2];                 \
          n2_ = (m >= a && m >= b) ? m : 0.0f; }                                      \
        { float m = M3[w1]; int c = (cpv >> 6) & 3;                                   \
          float a = (c==0)?M2[w1]:(c==1)?M2[w0]:(c==2)?M3[w0]:Mrgt[w0];               \
          float b = (c==0)?Mrgt[w1]:(c==1)?Mrgt[w2]:(c==2)?M3[w2]:M2[w2];             \
          n3_ = (m >= a && m >= b) ? m : 0.0f; }                                      \
        float env;                                                                    \
        { float m = Emc[w1]; int c = (cpv >> 8) & 3;                                  \
          float a = (c==0)?Eml[w1]:(c==1)?Eml[w0]:(c==2)?Emc[w0]:Emr[w0];             \
          float b = (c==0)?Emr[w1]:(c==1)?Emr[w2]:(c==2)?Emc[w2]:Eml[w2];             \
          env = (m >= a && m >= b) ? m : 0.0f; }                                      \
        unsigned sm_ = (n0_ >= high ? 1u : 0u) | (n1_ >= high ? 2u : 0u)              \
                     | (n2_ >= high ? 4u : 0u) | (n3_ >= high ? 8u : 0u);             \
        unsigned eb_ = (env >= high) ? 1u : 0u;                                       \
        unsigned su_ = (unsigned)__shfl_up((int)sm_, 1);                              \
        unsigned sd_ = (unsigned)__shfl_down((int)sm_, 1);                            \
        unsigned lb_ = L0 ? eb_ : ((su_ >> 3) & 1u);                                  \
        unsigned rb_ = L63 ? eb_ : (sd_ & 1u);                                        \
        N0[sp2] = n0_; N1[sp2] = n1_; N2[sp2] = n2_; N3[sp2] = n3_;                   \
        Rm[sp2] = lb_ | (sm_ << 1) | (rb_ << 5);                                      \
    }                                                                                 \
    if (DO_OUT) {                                                                     \
        constexpr int z0 = s_, z1 = sp1, z2 = sp2;                                    \
        int Rh = h0 + (kk) - 6;                                                       \
        unsigned comb = Rm[z0] | Rm[z1] | Rm[z2];                                     \
        unsigned dil  = comb | (comb << 1) | (comb >> 1);                             \
        unsigned srow = Rm[z1];                                                       \
        float4 e4;                                                                    \
        e4.x = (((srow >> 1) & 1u) | (((dil >> 1) & 1u) & (N0[z1] >= low ? 1u : 0u))) \
               ? 1.0f : 0.0f;                                                         \
        e4.y = (((srow >> 2) & 1u) | (((dil >> 2) & 1u) & (N1[z1] >= low ? 1u : 0u))) \
               ? 1.0f : 0.0f;                                                         \
        e4.z = (((srow >> 3) & 1u) | (((dil >> 3) & 1u) & (N2[z1] >= low ? 1u : 0u))) \
               ? 1.0f : 0.0f;                                                         \
        e4.w = (((srow >> 4) & 1u) | (((dil >> 4) & 1u) & (N3[z1] >= low ? 1u : 0u))) \
               ? 1.0f : 0.0f;                                                         \
        if (Rh <= 512)                                                                \
            *(float4*)(od + (size_t)(Rh - 1) * HW + j0 + 4 * lane) = e4;              \
    }                                                                                 \
} while (0)

__global__ __launch_bounds__(256) void k_fused(const float* __restrict__ x,
                                               const unsigned int* __restrict__ smax,
                                               float* __restrict__ out) {
    const int lane = threadIdx.x, ty = threadIdx.y;
    const int d  = blockIdx.z;
    const int j0 = blockIdx.x * 256;                   // x/out col base (0 or 256)
    const int h0 = 1 + (blockIdx.y * 4 + ty) * 22;     // 24 strips x 22 out rows
    const float* xd = x + (size_t)d * HW * HW;
    float* od = out + (size_t)d * HW * HW;
    const bool L0 = (lane == 0), L63 = (lane == 63);
    const bool hland = (lane < 3) | (lane >= 61);
    int hg = j0 + ((lane < 3) ? (lane - 2) : (lane + 196));
    hg += (hg < 0) ? MG : 0;  hg -= (hg >= MG) ? MG : 0;
    const bool hok   = (unsigned)(hg - 1) < (unsigned)HW;
    const int  hcolv = hok ? (hg - 1) : 0;

    const float high = __uint_as_float(smax[d]) * 0.05f;
    const float low  = high * 0.01f;

    float Xc0[3], Xc1[3], Xc2[3], Xc3[3], Xl[3], Xr[3], E0[3], E1[3], E2[3];
    float M0[3], M1[3], M2[3], M3[3], Mlft[3], Mrgt[3], Emc[3], Eml[3], Emr[3];
    unsigned CP[3], Rm[3];
    float N0[3], N1[3], N2[3], N3[3];

    P2BODY(0, 0, 0, 0, 0);
    P2BODY(1, 1, 0, 0, 0);
    P2BODY(2, 2, 1, 0, 0);
    P2BODY(3, 0, 1, 0, 0);
    P2BODY(4, 1, 1, 1, 0);
    P2BODY(5, 2, 1, 1, 0);
    #pragma unroll 1
    for (int kb = 6; kb < 27; kb += 3) {               // kk = 6..26
        P2BODY(kb + 0, 0, 1, 1, 1);
        P2BODY(kb + 1, 1, 1, 1, 1);
        P2BODY(kb + 2, 2, 1, 1, 1);
    }
    P2BODY(27, 0, 1, 1, 1);                            // t = 21 (last row of strip)
}

extern "C" void kernel_launch(void* const* d_in, const int* in_sizes, int n_in,
                              void* d_out, int out_size, void* d_ws, size_t ws_size,
                              hipStream_t stream) {
    const float* x = (const float*)d_in[0];
    float* out = (float*)d_out;
    unsigned int* smax = (unsigned int*)d_ws;          // 128 * 4B only

    hipMemsetAsync(smax, 0, DD * sizeof(unsigned int), stream);

    dim3 blk(64, 4, 1);
    k_max1 <<<dim3(1, 15, DD), blk, 0, stream>>>(x, smax);
    k_fused<<<dim3(2, 6, DD), blk, 0, stream>>>(x, smax, out);
}

// Round 26
// 168.303 us; speedup vs baseline: 1.0220x; 1.0220x over previous
//
#include <hip/hip_runtime.h>
#include <math.h>

#define DD 128
#define HW 512
#define MG 514

// Verified reference stack (r10/r11/r14): G1 predux-tree colmajor conv,
// contract-off mul/add mag, fd-hybrid classifier.
// r26 = r24 verbatim (measured best: 167.7 us; k_fused 127.6 @ 82% VALUBusy,
// k_max1 40). r25's instruction-mix changes were neutral-to-negative;
// k_fused is issue-bound (~2x hand-counted minimum, codegen-limited).

static __device__ float fd_atanf(float x) {
    #pragma clang fp contract(off)
    const unsigned hx = __float_as_uint(x);
    const unsigned ix = hx & 0x7fffffffu;
    const double A0 = 0.46364760900080611621425623146121440203;
    const double A1 = 0.78539816339744830961566084581987572105;
    const double A2 = 0.98279372324732906798571061101466601449;
    const double A3 = 1.57079632679489661923132169163975144210;
    const float aT0 =  3.3333328366e-01f;
    const float aT1 = -1.9999158382e-01f;
    const float aT2 =  1.4253635705e-01f;
    const float aT3 = -1.0648017377e-01f;
    const float aT4 =  6.1687607318e-02f;
    float z, w, s1, s2;
    int id;
    double a;
    if (ix >= 0x4c800000u) {
        a = A3;
        float hi = (float)a; if ((double)hi > a) hi = __uint_as_float(__float_as_uint(hi) - 1u);
        float lo = (float)(a - (double)hi);
        float r = hi + lo;
        return (hx >> 31) ? -r : r;
    }
    if (ix < 0x3ee00000u) {
        if (ix < 0x39800000u) return x;
        id = -1;
    } else {
        x = fabsf(x);
        if (ix < 0x3f980000u) {
            if (ix < 0x3f300000u) { id = 0; x = (2.0f * x - 1.0f) / (2.0f + x); }
            else                  { id = 1; x = (x - 1.0f) / (x + 1.0f); }
        } else {
            if (ix < 0x401c0000u) { id = 2; x = (x - 1.5f) / (1.0f + 1.5f * x); }
            else                  { id = 3; x = -1.0f / x; }
        }
    }
    z = x * x;
    w = z * z;
    s1 = z * (aT0 + w * (aT2 + w * aT4));
    s2 = w * (aT1 + w * aT3);
    if (id < 0) return x - x * (s1 + s2);
    a = (id == 0) ? A0 : (id == 1) ? A1 : (id == 2) ? A2 : A3;
    float hi = (float)a; if ((double)hi > a) hi = __uint_as_float(__float_as_uint(hi) - 1u);
    float lo = (float)(a - (double)hi);
    z = hi - ((x * (s1 + s2) - lo) - x);
    return (hx >> 31) ? -z : z;
}

static __device__ __noinline__ int cls_fd(float y, float x) {
    #pragma clang fp contract(off)
    const unsigned hx = __float_as_uint(x), hy = __float_as_uint(y);
    const unsigned ix = hx & 0x7fffffffu, iy = hy & 0x7fffffffu;
    unsigned m = ((hy >> 31) & 1u) | ((hx >> 30) & 2u);
    const double PI_D = 3.14159265358979323846264338327950288420;
    const float pi_f  = (float)PI_D;
    const float pi_lo = (float)(PI_D - (double)pi_f);
    const float pi4_f = (float)(PI_D / 4.0);
    const float pi2_f = (float)(PI_D / 2.0);
    float v;
    if (iy == 0) {
        v = (m == 0 || m == 1) ? y : (m == 2 ? pi_f : -pi_f);
    } else if (ix == 0) {
        v = (m & 1u) ? -pi2_f : pi2_f;
    } else if (ix + (26u << 23) < iy) {
        v = (m & 1u) ? -pi2_f : pi2_f;
    } else {
        float z;
        if ((m & 2u) && iy + (26u << 23) < ix) z = 0.0f;
        else z = fd_atanf(fabsf(y / x));
        switch (m) {
            case 0:  v = z; break;
            case 1:  v = -z; break;
            case 2:  v = pi_f - (z - pi_lo); break;
            default: v = (z - pi_lo) - pi_f; break;
        }
    }
    float t = v / pi4_f;
    int n = (int)rintf(t);
    return n & 3;
}

static __device__ __forceinline__ int classify(float gx, float gy) {
    #pragma clang fp contract(off)
    float ax = fabsf(gx), ay = fabsf(gy);
    const float T = 0.41421356237309504880f;
    float r1 = ay - ax * T;
    float r2 = ax - ay * T;
    float eps = 1e-4f * (ax + ay);
    if (fabsf(r1) > eps && fabsf(r2) > eps) {
        if (r1 < 0.0f) return 0;
        if (r2 < 0.0f) return 2;
        return ((__float_as_uint(gx) ^ __float_as_uint(gy)) >> 31) ? 3 : 1;
    }
    return cls_fd(gy, gx);
}

static __device__ __forceinline__ void grad_g1v(float x00, float x01, float x02,
                                                float x10, float x12,
                                                float x20, float x21, float x22,
                                                float& gx, float& gy) {
    #pragma clang fp contract(off)
    { float A = -x00; float B = x02 + (-x20); float C = 2.0f*x12; float D = -2.0f*x10;
      float E = A + B; float F = C + D; gx = (E + F) + x22; }
    { float A = -x00; float B = (-x02) + x20; float C = -2.0f*x01; float D = 2.0f*x21;
      float E = A + B; float F = C + D; gy = (E + F) + x22; }
}

static __device__ __forceinline__ float mag2(float gx, float gy) {
    #pragma clang fp contract(off)
    float p = gx * gx;
    float q = gy * gy;
    return sqrtf(p + q);
}
static __device__ __forceinline__ float sq2(float gx, float gy) {
    #pragma clang fp contract(off)
    float p = gx * gx;
    float q = gy * gy;
    return p + q;
}

#define LOADROW(S_, ROWEXPR) do {                                                     \
    int Rx_ = (ROWEXPR);                                                              \
    int W_ = Rx_;  W_ += (W_ < 0) ? MG : 0;  W_ -= (W_ >= MG) ? MG : 0;               \
    float4 xv_ = float4{0.f, 0.f, 0.f, 0.f}; float hv_ = 0.f;                         \
    if ((unsigned)(W_ - 1) < (unsigned)HW) {                                          \
        const float* rowp_ = xd + (size_t)(W_ - 1) * HW;                              \
        xv_ = *(const float4*)(rowp_ + j0 + 4 * lane);                                \
        if (hland && hok) hv_ = rowp_[hcolv];                                         \
    }                                                                                 \
    float hA_ = __shfl(hv_, 0),  hB_ = __shfl(hv_, 1),  hC_ = __shfl(hv_, 2);         \
    float hD_ = __shfl(hv_, 61), hE_ = __shfl(hv_, 62), hF_ = __shfl(hv_, 63);        \
    float xlv_ = __shfl_up(xv_.w, 1);   if (L0)  xlv_ = hC_;                          \
    float xrv_ = __shfl_down(xv_.x, 1); if (L63) xrv_ = hD_;                          \
    Xc0[S_] = xv_.x; Xc1[S_] = xv_.y; Xc2[S_] = xv_.z; Xc3[S_] = xv_.w;               \
    Xl[S_] = xlv_; Xr[S_] = xrv_;                                                     \
    E0[S_] = L0 ? hA_ : hD_; E1[S_] = L0 ? hB_ : hE_; E2[S_] = L0 ? hC_ : hF_;        \
} while (0)

#define MAGS6_F(u0, u1, u2, MAGFN)                                                    \
    float gx0, gy0, gx1, gy1, gx2, gy2, gx3, gy3;                                     \
    grad_g1v(Xl[u0], Xc0[u0], Xc1[u0], Xl[u1], Xc1[u1],                               \
             Xl[u2], Xc0[u2], Xc1[u2], gx0, gy0);                                     \
    grad_g1v(Xc0[u0], Xc1[u0], Xc2[u0], Xc0[u1], Xc2[u1],                             \
             Xc0[u2], Xc1[u2], Xc2[u2], gx1, gy1);                                    \
    grad_g1v(Xc1[u0], Xc2[u0], Xc3[u0], Xc1[u1], Xc3[u1],                             \
             Xc1[u2], Xc2[u2], Xc3[u2], gx2, gy2);                                    \
    grad_g1v(Xc2[u0], Xc3[u0], Xr[u0], Xc2[u1], Xr[u1],                               \
             Xc2[u2], Xc3[u2], Xr[u2], gx3, gy3);                                     \
    float m0_ = MAGFN(gx0, gy0), m1_ = MAGFN(gx1, gy1);                               \
    float m2_ = MAGFN(gx2, gy2), m3_ = MAGFN(gx3, gy3);                               \
    float A0_ = L0 ? E0[u0] : Xc3[u0], B0_ = L0 ? E1[u0] : E0[u0];                    \
    float C0_ = L0 ? E2[u0] : E1[u0],  D0_ = L0 ? Xc0[u0] : E2[u0];                   \
    float A1_ = L0 ? E0[u1] : Xc3[u1], B1_ = L0 ? E1[u1] : E0[u1];                    \
    float C1_ = L0 ? E2[u1] : E1[u1],  D1_ = L0 ? Xc0[u1] : E2[u1];                   \
    float A2_ = L0 ? E0[u2] : Xc3[u2], B2_ = L0 ? E1[u2] : E0[u2];                    \
    float C2_ = L0 ? E2[u2] : E1[u2],  D2_ = L0 ? Xc0[u2] : E2[u2];                   \
    float g1x, g1y, g2x, g2y;                                                         \
    grad_g1v(A0_, B0_, C0_, A1_, C1_, A2_, B2_, C2_, g1x, g1y);                       \
    grad_g1v(B0_, C0_, D0_, B1_, D1_, B2_, C2_, D2_, g2x, g2y);                       \
    float em1 = MAGFN(g1x, g1y), em2 = MAGFN(g2x, g2y);

// ---------------- pass 1: per-slice max of (gx^2+gy^2); sqrt once ----------------
#define M1BODY(kk, S, DOMAG) do {                                                     \
    constexpr int s_ = (S);                                                           \
    constexpr int u0 = (s_ + 1) % 3, u1 = (s_ + 2) % 3, u2 = s_;                      \
    LOADROW(s_, h0m - 1 + (kk));                                                      \
    if (DOMAG) {                                                                      \
        int Rm = h0m - 2 + (kk);                                                      \
        if (Rm <= 513) {                                                              \
            MAGS6_F(u0, u1, u2, sq2)                                                  \
            acc = fmaxf(acc, fmaxf(fmaxf(m0_, m1_), fmaxf(m2_, m3_)));                \
            if (L0 || L63) acc = fmaxf(acc, fmaxf(em1, em2));                         \
        }                                                                             \
    }                                                                                 \
} while (0)

__global__ __launch_bounds__(256) void k_max1(const float* __restrict__ x,
                                              unsigned int* __restrict__ smax) {
    const int lane = threadIdx.x, ty = threadIdx.y;
    const int d  = blockIdx.z;
    const int j0 = blockIdx.x * 256;
    const int h0m = (blockIdx.y * 4 + ty) * 33;      // 16 strips x 33 mag rows
    const float* xd = x + (size_t)d * HW * HW;
    const bool L0 = (lane == 0), L63 = (lane == 63);
    const bool hland = (lane < 3) | (lane >= 61);
    int hg = j0 + ((lane < 3) ? (lane - 2) : (lane + 196));
    hg += (hg < 0) ? MG : 0;  hg -= (hg >= MG) ? MG : 0;
    const bool hok   = (unsigned)(hg - 1) < (unsigned)HW;
    const int  hcolv = hok ? (hg - 1) : 0;

    float Xc0[3], Xc1[3], Xc2[3], Xc3[3], Xl[3], Xr[3], E0[3], E1[3], E2[3];
    float acc = 0.0f;

    M1BODY(0, 0, 0); M1BODY(1, 1, 0);
    #pragma unroll
    for (int kb = 2; kb < 35; kb += 3) {             // 11 triples: kk = 2..34
        M1BODY(kb + 0, 2, 1);
        M1BODY(kb + 1, 0, 1);
        M1BODY(kb + 2, 1, 1);
    }

    for (int off = 32; off > 0; off >>= 1)
        acc = fmaxf(acc, __shfl_down(acc, off, 64));
    if (lane == 0) {
        float mx = sqrtf(acc);   // CR sqrt monotone: sqrt(max sq) == max(sqrt sq)
        atomicMax(smax + d, __float_as_uint(mx));
    }
}

// ---------------- pass 2: fused mag/cls/NMS/threshold/hysteresis ----------------
#define P2BODY(kk, S, DO_MAG, DO_NMS, DO_OUT) do {                                    \
    constexpr int s_ = (S);                                                           \
    constexpr int sp1 = (s_ + 1) % 3, sp2 = (s_ + 2) % 3;                             \
    LOADROW(s_, h0 - 3 + (kk));                                                       \
    if (DO_MAG) {                                                                     \
        MAGS6_F(sp1, sp2, s_, mag2)                                                   \
        float mlv = __shfl_up(m3_, 1);   if (L0)  mlv = em2;                          \
        float mrv = __shfl_down(m0_, 1); if (L63) mrv = em1;                          \
        M0[sp1] = m0_; M1[sp1] = m1_; M2[sp1] = m2_; M3[sp1] = m3_;                   \
        Mlft[sp1] = mlv; Mrgt[sp1] = mrv;                                             \
        Emc[sp1] = L0 ? em2 : em1;                                                    \
        Eml[sp1] = L0 ? em1 : m3_;                                                    \
        Emr[sp1] = L0 ? m0_ : em2;                                                    \
        C0[sp1] = classify(gx0, gy0); C1[sp1] = classify(gx1, gy1);                   \
        C2[sp1] = classify(gx2, gy2); C3[sp1] = classify(gx3, gy3);                   \
        Ecl[sp1] = classify(L0 ? g2x : g1x, L0 ? g2y : g1y);                          \
    }                                                                                 \
    if (DO_NMS) {                                                                     \
        constexpr int w0 = sp2, w1 = s_, w2 = sp1;                                    \
        float n0_, n1_, n2_, n3_;                                                     \
        { float m = M0[w1]; int c = C0[w1];                                           \
          float a = (c==0)?Mlft[w1]:(c==1)?Mlft[w0]:(c==2)?M0[w0]:M1[w0];             \
          float b = (c==0)?M1[w1]:(c==1)?M1[w2]:(c==2)?M0[w2]:Mlft[w2];               \
          n0_ = (m >= a && m >= b) ? m : 0.0f; }                                      \
        { float m = M1[w1]; int c = C1[w1];                                           \
          float a = (c==0)?M0[w1]:(c==1)?M0[w0]:(c==2)?M1[w0]:M2[w0];                 \
          float b = (c==0)?M2[w1]:(c==1)?M2[w2]:(c==2)?M1[w2]:M0[w2];                 \
          n1_ = (m >= a && m >= b) ? m : 0.0f; }                                      \
        { float m = M2[w1]; int c = C2[w1];                                           \
          float a = (c==0)?M1[w1]:(c==1)?M1[w0]:(c==2)?M2[w0]:M3[w0];                 \
          float b = (c==0)?M3[w1]:(c==1)?M3[w2]:(c==2)?M2[w2]:M1[w2];                 \
          n2_ = (m >= a && m >= b) ? m : 0.0f; }                                      \
        { float m = M3[w1]; int c = C3[w1];                                           \
          float a = (c==0)?M2[w1]:(c==1)?M2[w0]:(c==2)?M3[w0]:Mrgt[w0];               \
          float b = (c==0)?Mrgt[w1]:(c==1)?Mrgt[w2]:(c==2)?M3[w2]:M2[w2];             \
          n3_ = (m >= a && m >= b) ? m : 0.0f; }                                      \
        float env;                                                                    \
        { float m = Emc[w1]; int c = Ecl[w1];                                         \
          float a = (c==0)?Eml[w1]:(c==1)?Eml[w0]:(c==2)?Emc[w0]:Emr[w0];             \
          float b = (c==0)?Emr[w1]:(c==1)?Emr[w2]:(c==2)?Emc[w2]:Eml[w2];             \
          env = (m >= a && m >= b) ? m : 0.0f; }                                      \
        float nlv = __shfl_up(n3_, 1);   if (L0)  nlv = env;                          \
        float nrv = __shfl_down(n0_, 1); if (L63) nrv = env;                          \
        N0[sp2] = n0_; N1[sp2] = n1_; N2[sp2] = n2_; N3[sp2] = n3_;                   \
        Nl[sp2] = nlv; Nr[sp2] = nrv;                                                 \
    }                                                                                 \
    if (DO_OUT) {                                                                     \
        constexpr int z0 = s_, z1 = sp1, z2 = sp2;                                    \
        int Rh = h0 + (kk) - 6;                                                       \
        float4 e4;                                                                    \
        { float m = N0[z1]; float e;                                                  \
          if (m >= high) e = 1.0f;                                                    \
          else if (m >= low) {                                                        \
            bool p = Nl[z0]>=high || N0[z0]>=high || N1[z0]>=high ||                  \
                     Nl[z1]>=high ||                  N1[z1]>=high ||                 \
                     Nl[z2]>=high || N0[z2]>=high || N1[z2]>=high;                    \
            e = p ? 1.0f : 0.0f; } else e = 0.0f;                                     \
          e4.x = e; }                                                                 \
        { float m = N1[z1]; float e;                                                  \
          if (m >= high) e = 1.0f;                                                    \
          else if (m >= low) {                                                        \
            bool p = N0[z0]>=high || N1[z0]>=high || N2[z0]>=high ||                  \
                     N0[z1]>=high ||                  N2[z1]>=high ||                 \
                     N0[z2]>=high || N1[z2]>=high || N2[z2]>=high;                    \
            e = p ? 1.0f : 0.0f; } else e = 0.0f;                                     \
          e4.y = e; }                                                                 \
        { float m = N2[z1]; float e;                                                  \
          if (m >= high) e = 1.0f;                                                    \
          else if (m >= low) {                                                        \
            bool p = N1[z0]>=high || N2[z0]>=high || N3[z0]>=high ||                  \
                     N1[z1]>=high ||                  N3[z1]>=high ||                 \
                     N1[z2]>=high || N2[z2]>=high || N3[z2]>=high;                    \
            e = p ? 1.0f : 0.0f; } else e = 0.0f;                                     \
          e4.z = e; }                                                                 \
        { float m = N3[z1]; float e;                                                  \
          if (m >= high) e = 1.0f;                                                    \
          else if (m >= low) {                                                        \
            bool p = N2[z0]>=high || N3[z0]>=high || Nr[z0]>=high ||                  \
                     N2[z1]>=high ||                  Nr[z1]>=high ||                 \
                     N2[z2]>=high || N3[z2]>=high || Nr[z2]>=high;                    \
            e = p ? 1.0f : 0.0f; } else e = 0.0f;                                     \
          e4.w = e; }                                                                 \
        if (Rh <= 512)                                                                \
            *(float4*)(od + (size_t)(Rh - 1) * HW + j0 + 4 * lane) = e4;              \
    }                                                                                 \
} while (0)

__global__ __launch_bounds__(256) void k_fused(const float* __restrict__ x,
                                               const unsigned int* __restrict__ smax,
                                               float* __restrict__ out) {
    const int lane = threadIdx.x, ty = threadIdx.y;
    const int d  = blockIdx.z;
    const int j0 = blockIdx.x * 256;                   // x/out col base (0 or 256)
    const int h0 = 1 + (blockIdx.y * 4 + ty) * 22;     // 24 strips x 22 out rows
    const float* xd = x + (size_t)d * HW * HW;
    float* od = out + (size_t)d * HW * HW;
    const bool L0 = (lane == 0), L63 = (lane == 63);
    const bool hland = (lane < 3) | (lane >= 61);
    int hg = j0 + ((lane < 3) ? (lane - 2) : (lane + 196));
    hg += (hg < 0) ? MG : 0;  hg -= (hg >= MG) ? MG : 0;
    const bool hok   = (unsigned)(hg - 1) < (unsigned)HW;
    const int  hcolv = hok ? (hg - 1) : 0;

    const float high = __uint_as_float(smax[d]) * 0.05f;
    const float low  = high * 0.01f;

    float Xc0[3], Xc1[3], Xc2[3], Xc3[3], Xl[3], Xr[3], E0[3], E1[3], E2[3];
    float M0[3], M1[3], M2[3], M3[3], Mlft[3], Mrgt[3], Emc[3], Eml[3], Emr[3];
    int   C0[3], C1[3], C2[3], C3[3], Ecl[3];
    float N0[3], N1[3], N2[3], N3[3], Nl[3], Nr[3];

    P2BODY(0, 0, 0, 0, 0);
    P2BODY(1, 1, 0, 0, 0);
    P2BODY(2, 2, 1, 0, 0);
    P2BODY(3, 0, 1, 0, 0);
    P2BODY(4, 1, 1, 1, 0);
    P2BODY(5, 2, 1, 1, 0);
    #pragma unroll 1
    for (int kb = 6; kb < 27; kb += 3) {               // kk = 6..26
        P2BODY(kb + 0, 0, 1, 1, 1);
        P2BODY(kb + 1, 1, 1, 1, 1);
        P2BODY(kb + 2, 2, 1, 1, 1);
    }
    P2BODY(27, 0, 1, 1, 1);                            // t = 21 (last row of strip)
}

extern "C" void kernel_launch(void* const* d_in, const int* in_sizes, int n_in,
                              void* d_out, int out_size, void* d_ws, size_t ws_size,
                              hipStream_t stream) {
    const float* x = (const float*)d_in[0];
    float* out = (float*)d_out;
    unsigned int* smax = (unsigned int*)d_ws;          // 128 * 4B only

    hipMemsetAsync(smax, 0, DD * sizeof(unsigned int), stream);

    dim3 blk(64, 4, 1);
    k_max1 <<<dim3(2, 4, DD), blk, 0, stream>>>(x, smax);
    k_fused<<<dim3(2, 6, DD), blk, 0, stream>>>(x, smax, out);
}